// Round 8
// baseline (257.957 us; speedup 1.0000x reference)
//
#include <hip/hip_runtime.h>
#include <hip/hip_bf16.h>

#define EMB 10
#define DIN 36    // 2*EMB + 16 numeric
#define HID 128
#define BM  128   // rows per block

typedef __attribute__((ext_vector_type(8))) short short8;   // bf16x8 MFMA frag
typedef __attribute__((ext_vector_type(4))) float f32x4;    // fp32x4 acc frag

union U8 { unsigned u[4]; short8 v; };

__device__ __forceinline__ short bf16_hi(float v) {
  __hip_bfloat16 h = __float2bfloat16(v);
  return *reinterpret_cast<short*>(&h);
}
__device__ __forceinline__ float bf16_to_f(short s) {
  __hip_bfloat16 h = *reinterpret_cast<__hip_bfloat16*>(&s);
  return __bfloat162float(h);
}

// Truncation hi/lo split for a PAIR of floats, packed via v_perm_b32.
__device__ __forceinline__ void split_pair(float a, float b, unsigned &hi, unsigned &lo) {
  unsigned ua = __float_as_uint(a), ub = __float_as_uint(b);
  hi = __builtin_amdgcn_perm(ub, ua, 0x07060302u);   // [hi16(b) : hi16(a)]
  float ra = a - __uint_as_float(ua & 0xFFFF0000u);
  float rb = b - __uint_as_float(ub & 0xFFFF0000u);
  lo = __builtin_amdgcn_perm(__float_as_uint(rb), __float_as_uint(ra), 0x07060302u);
}

// Pack W1 (36x128) + b1 (k=36 bias row) into hi/lo bf16 B-fragments, K padded 64.
// Layout: [term(2)][ct(8)][ks(2)][lane(64)][e(8)] bf16.
__global__ void prep_kernel(const float* __restrict__ W1, const float* __restrict__ b1,
                            short* __restrict__ Bpack) {
  int b = blockIdx.x;          // 32 blocks
  int term = b >> 4;
  int ct   = (b >> 1) & 7;
  int ks   = b & 1;
  int l = threadIdx.x;         // 0..63
  int col = ct * 16 + (l & 15);
  int kb  = ks * 32 + (l >> 4) * 8;
  short8 o;
#pragma unroll
  for (int e = 0; e < 8; ++e) {
    int k = kb + e;
    float v = 0.0f;
    if (k < DIN)       v = W1[k * HID + col];
    else if (k == DIN) v = b1[col];
    short hb = bf16_hi(v);
    o[e] = (term == 0) ? hb : bf16_hi(v - bf16_to_f(hb));
  }
  *(short8*)(Bpack + (size_t)(((term * 8 + ct) * 2 + ks) * 64 + l) * 8) = o;
}

// ONE-BARRIER direct-fragment kernel: gather halo -> barrier -> each MFMA
// thread computes its own windowed means straight from E-LDS (no Cs, no
// build phase, no second barrier). Chain: idx -> gather -> barrier -> compute.
__global__ __launch_bounds__(256)
void fused_kernel(const int* __restrict__ t1, const int* __restrict__ t2,
                  const float* __restrict__ numf,
                  const float* __restrict__ tab1, const float* __restrict__ tab2,
                  const short* __restrict__ Bpack,
                  const float* __restrict__ W2, const float* __restrict__ b2,
                  float* __restrict__ out, int N) {
  __shared__ float E1[130][10];     // halo rows base-1 .. base+128
  __shared__ float E2[134][10];     // halo rows base-3 .. base+130

  const int tid = threadIdx.x;
  const long base = (long)blockIdx.x * BM;
  const int wid = tid >> 6, l = tid & 63;
  const int arow = l & 15, kg = l >> 4;

  // ---- numeric loads for this thread's fragment slots (issued first) ----
  const long rg0 = base + (long)(wid * 2) * 16 + arow;
  const long rg1 = rg0 + 16;
  float4 qa0 = {0,0,0,0}, qa1 = {0,0,0,0}, qb0 = {0,0,0,0}, qb1 = {0,0,0,0};
  if (kg == 0) {                    // ks1 frag: n12-15 (offset 48B, 16B-aligned)
    if (rg0 < (long)N) qa0 = *(const float4*)(numf + rg0 * 16 + 12);
    if (rg1 < (long)N) qa1 = *(const float4*)(numf + rg1 * 16 + 12);
  } else if (kg == 2) {             // k20-23: n0-3
    if (rg0 < (long)N) qa0 = *(const float4*)(numf + rg0 * 16);
    if (rg1 < (long)N) qa1 = *(const float4*)(numf + rg1 * 16);
  } else if (kg == 3) {             // k24-31: n4-11
    if (rg0 < (long)N) { qa0 = *(const float4*)(numf + rg0 * 16 + 4);
                         qb0 = *(const float4*)(numf + rg0 * 16 + 8); }
    if (rg1 < (long)N) { qa1 = *(const float4*)(numf + rg1 * 16 + 4);
                         qb1 = *(const float4*)(numf + rg1 * 16 + 8); }
  }
  // W2 column weights + b2 (independent; hide under gathers)
  float w2r[8];
#pragma unroll
  for (int ct = 0; ct < 8; ++ct) w2r[ct] = W2[ct * 16 + (l & 15)];
  const float b2v = b2[0];

  // ---- halo gathers (zero-fill outside array) ----
  if (tid < 130) {
    long g = base - 1 + tid;
    if (g >= 0 && g < (long)N) {
      const float2* src = (const float2*)(tab1 + (long)t1[g] * EMB);
#pragma unroll
      for (int i = 0; i < 5; ++i) {
        float2 v = src[i];
        E1[tid][2 * i] = v.x; E1[tid][2 * i + 1] = v.y;
      }
    } else {
#pragma unroll
      for (int i = 0; i < EMB; ++i) E1[tid][i] = 0.0f;
    }
  }
  {
    int h2 = tid - 122;             // tid 122..255 -> h2 0..133
    if (h2 >= 0) {
      long g = base - 3 + h2;
      if (g >= 0 && g < (long)N) {
        const float2* src = (const float2*)(tab2 + (long)t2[g] * EMB);
#pragma unroll
        for (int i = 0; i < 5; ++i) {
          float2 v = src[i];
          E2[h2][2 * i] = v.x; E2[h2][2 * i + 1] = v.y;
        }
      } else {
#pragma unroll
        for (int i = 0; i < EMB; ++i) E2[h2][i] = 0.0f;
      }
    }
  }
  __syncthreads();   // the only barrier

  // ---- fragment build: windowed means computed by the consumer thread ----
  // A frag (16x16x32): row = lane&15, k = ks*32 + kg*8 + e.
  // k 0-9 = e1 mean3, k 10-19 = e2 mean7, k 20-35 = numeric, k36 = bias.
  const bool edgeblk = (base == 0) || (base + BM + 3 > (long)N);
  short8 aHi[2][2], aLo[2][2];
#pragma unroll
  for (int rtl = 0; rtl < 2; ++rtl) {
    const int row0 = (wid * 2 + rtl) * 16 + arow;   // 0..127
    const long g = base + row0;
    const float4 qa = rtl ? qa1 : qa0;
    const float4 qb = rtl ? qb1 : qb0;
    float inv1 = (1.0f / 3.0f), inv2 = (1.0f / 7.0f);
    if (edgeblk) {
      long lo1 = g - 1; if (lo1 < 0) lo1 = 0;
      long hi1 = g + 2; if (hi1 > (long)N) hi1 = (long)N;
      long c1 = hi1 - lo1; if (c1 < 1) c1 = 1;
      inv1 = 1.0f / (float)c1;
      long lo2 = g - 3; if (lo2 < 0) lo2 = 0;
      long hi2 = g + 4; if (hi2 > (long)N) hi2 = (long)N;
      long c2 = hi2 - lo2; if (c2 < 1) c2 = 1;
      inv2 = 1.0f / (float)c2;
    }
    U8 h0, l0, h1, l1;
    h1.u[0] = h1.u[1] = h1.u[2] = h1.u[3] = 0u;
    l1.u[0] = l1.u[1] = l1.u[2] = l1.u[3] = 0u;
    if (kg == 0) {
      // k0-7 = e1 d0-7, window rows row0..row0+2 in halo coords
      float v[8];
#pragma unroll
      for (int j = 0; j < 4; ++j) {
        float2 x0 = *(const float2*)&E1[row0    ][2 * j];
        float2 x1 = *(const float2*)&E1[row0 + 1][2 * j];
        float2 x2 = *(const float2*)&E1[row0 + 2][2 * j];
        v[2 * j]     = (x0.x + x1.x + x2.x) * inv1;
        v[2 * j + 1] = (x0.y + x1.y + x2.y) * inv1;
      }
      split_pair(v[0], v[1], h0.u[0], l0.u[0]);
      split_pair(v[2], v[3], h0.u[1], l0.u[1]);
      split_pair(v[4], v[5], h0.u[2], l0.u[2]);
      split_pair(v[6], v[7], h0.u[3], l0.u[3]);
      // ks1: k32-35 = n12-15, k36 = bias 1.0
      split_pair(qa.x, qa.y, h1.u[0], l1.u[0]);
      split_pair(qa.z, qa.w, h1.u[1], l1.u[1]);
      h1.u[2] = 0x00003F80u;   // bf16(1.0) in k36, k37 = 0
    } else if (kg == 1) {
      // k8-9 = e1 d8-9
      float2 x0 = *(const float2*)&E1[row0    ][8];
      float2 x1 = *(const float2*)&E1[row0 + 1][8];
      float2 x2 = *(const float2*)&E1[row0 + 2][8];
      float v0 = (x0.x + x1.x + x2.x) * inv1;
      float v1 = (x0.y + x1.y + x2.y) * inv1;
      // k10-15 = e2 d0-5, window rows row0..row0+6 in halo coords
      float s0 = 0, s1 = 0, s2 = 0, s3 = 0, s4 = 0, s5 = 0;
#pragma unroll
      for (int dh = 0; dh < 7; ++dh) {
        const float* er = &E2[row0 + dh][0];
        float2 y0 = *(const float2*)(er + 0);
        float2 y1 = *(const float2*)(er + 2);
        float2 y2 = *(const float2*)(er + 4);
        s0 += y0.x; s1 += y0.y; s2 += y1.x; s3 += y1.y; s4 += y2.x; s5 += y2.y;
      }
      split_pair(v0, v1, h0.u[0], l0.u[0]);
      split_pair(s0 * inv2, s1 * inv2, h0.u[1], l0.u[1]);
      split_pair(s2 * inv2, s3 * inv2, h0.u[2], l0.u[2]);
      split_pair(s4 * inv2, s5 * inv2, h0.u[3], l0.u[3]);
    } else if (kg == 2) {
      // k16-19 = e2 d6-9
      float s0 = 0, s1 = 0, s2 = 0, s3 = 0;
#pragma unroll
      for (int dh = 0; dh < 7; ++dh) {
        const float* er = &E2[row0 + dh][6];
        float2 y0 = *(const float2*)(er + 0);
        float2 y1 = *(const float2*)(er + 2);
        s0 += y0.x; s1 += y0.y; s2 += y1.x; s3 += y1.y;
      }
      split_pair(s0 * inv2, s1 * inv2, h0.u[0], l0.u[0]);
      split_pair(s2 * inv2, s3 * inv2, h0.u[1], l0.u[1]);
      // k20-23 = n0-3
      split_pair(qa.x, qa.y, h0.u[2], l0.u[2]);
      split_pair(qa.z, qa.w, h0.u[3], l0.u[3]);
    } else {
      // k24-31 = n4-11
      split_pair(qa.x, qa.y, h0.u[0], l0.u[0]);
      split_pair(qa.z, qa.w, h0.u[1], l0.u[1]);
      split_pair(qb.x, qb.y, h0.u[2], l0.u[2]);
      split_pair(qb.z, qb.w, h0.u[3], l0.u[3]);
    }
    aHi[rtl][0] = h0.v; aLo[rtl][0] = l0.v;
    aHi[rtl][1] = h1.v; aLo[rtl][1] = l1.v;
  }

  // ---- MFMA loop: 8 col-tiles, fused relu + W2 partial dot ----
  float part[2][4] = {{0,0,0,0},{0,0,0,0}};
#pragma unroll
  for (int ct = 0; ct < 8; ++ct) {
    short8 bh0 = *(const short8*)(Bpack + (size_t)(((0*8 + ct)*2 + 0)*64 + l)*8);
    short8 bh1 = *(const short8*)(Bpack + (size_t)(((0*8 + ct)*2 + 1)*64 + l)*8);
    short8 bl0 = *(const short8*)(Bpack + (size_t)(((1*8 + ct)*2 + 0)*64 + l)*8);
    short8 bl1 = *(const short8*)(Bpack + (size_t)(((1*8 + ct)*2 + 1)*64 + l)*8);
    float w2c = w2r[ct];
#pragma unroll
    for (int rtl = 0; rtl < 2; ++rtl) {
      f32x4 acc = {0.0f, 0.0f, 0.0f, 0.0f};
      acc = __builtin_amdgcn_mfma_f32_16x16x32_bf16(aHi[rtl][0], bh0, acc, 0, 0, 0);
      acc = __builtin_amdgcn_mfma_f32_16x16x32_bf16(aLo[rtl][0], bh0, acc, 0, 0, 0);
      acc = __builtin_amdgcn_mfma_f32_16x16x32_bf16(aHi[rtl][0], bl0, acc, 0, 0, 0);
      acc = __builtin_amdgcn_mfma_f32_16x16x32_bf16(aHi[rtl][1], bh1, acc, 0, 0, 0);
      acc = __builtin_amdgcn_mfma_f32_16x16x32_bf16(aLo[rtl][1], bh1, acc, 0, 0, 0);
      acc = __builtin_amdgcn_mfma_f32_16x16x32_bf16(aHi[rtl][1], bl1, acc, 0, 0, 0);
#pragma unroll
      for (int rg = 0; rg < 4; ++rg) {
        float hv = fmaxf(acc[rg], 0.0f);   // relu(h + b1), b1 via k36 bias row
        part[rtl][rg] += hv * w2c;
      }
    }
  }
  // reduce W2 dot across the 16 column-lanes
#pragma unroll
  for (int off = 1; off < 16; off <<= 1) {
#pragma unroll
    for (int rtl = 0; rtl < 2; ++rtl)
#pragma unroll
      for (int rg = 0; rg < 4; ++rg)
        part[rtl][rg] += __shfl_xor(part[rtl][rg], off, 64);
  }
  if ((l & 15) < 4) {
#pragma unroll
    for (int rtl = 0; rtl < 2; ++rtl) {
      int rt = wid * 2 + rtl;
      long grow = base + rt * 16 + (l >> 4) * 4 + (l & 15);
      if (grow < (long)N) {
        float x = part[rtl][l & 15] + b2v;
        out[grow] = 1.0f / (1.0f + exp2f(x * -1.44269504f));
      }
    }
  }
}

extern "C" void kernel_launch(void* const* d_in, const int* in_sizes, int n_in,
                              void* d_out, int out_size, void* d_ws, size_t ws_size,
                              hipStream_t stream) {
  const int*   t1   = (const int*)d_in[0];
  const int*   t2   = (const int*)d_in[1];
  const float* numf = (const float*)d_in[2];
  const float* tab1 = (const float*)d_in[3];
  const float* tab2 = (const float*)d_in[4];
  const float* W1   = (const float*)d_in[5];
  const float* b1   = (const float*)d_in[6];
  const float* W2   = (const float*)d_in[7];
  const float* b2   = (const float*)d_in[8];
  float* out = (float*)d_out;
  const int N = in_sizes[0];
  short* Bpack = (short*)d_ws;   // 32 KB

  hipLaunchKernelGGL(prep_kernel, dim3(32), dim3(64), 0, stream, W1, b1, Bpack);
  int nblk = (N + BM - 1) / BM;
  hipLaunchKernelGGL(fused_kernel, dim3(nblk), dim3(256), 0, stream,
                     t1, t2, numf, tab1, tab2, Bpack, W2, b2, out, N);
}

// Round 9
// 208.824 us; speedup vs baseline: 1.2353x; 1.2353x over previous
//
#include <hip/hip_runtime.h>
#include <hip/hip_bf16.h>

#define EMB 10
#define DIN 36    // 2*EMB + 16 numeric
#define HID 128
#define BM  128   // rows per tile
#define GRID 1024 // blocks; each owns ~ntiles/GRID contiguous tiles

typedef __attribute__((ext_vector_type(8))) short short8;   // bf16x8 MFMA frag
typedef __attribute__((ext_vector_type(4))) float f32x4;    // fp32x4 acc frag

union U8 { unsigned u[4]; short8 v; };

__device__ __forceinline__ short bf16_hi(float v) {
  __hip_bfloat16 h = __float2bfloat16(v);
  return *reinterpret_cast<short*>(&h);
}
__device__ __forceinline__ float bf16_to_f(short s) {
  __hip_bfloat16 h = *reinterpret_cast<__hip_bfloat16*>(&s);
  return __bfloat162float(h);
}

// Truncation hi/lo split for a PAIR of floats, packed via v_perm_b32.
__device__ __forceinline__ void split_pair(float a, float b, unsigned &hi, unsigned &lo) {
  unsigned ua = __float_as_uint(a), ub = __float_as_uint(b);
  hi = __builtin_amdgcn_perm(ub, ua, 0x07060302u);   // [hi16(b) : hi16(a)]
  float ra = a - __uint_as_float(ua & 0xFFFF0000u);
  float rb = b - __uint_as_float(ub & 0xFFFF0000u);
  lo = __builtin_amdgcn_perm(__float_as_uint(rb), __float_as_uint(ra), 0x07060302u);
}

// Pack W1 (36x128) + b1 (k=36 bias row) into hi/lo bf16 B-fragments, K padded 64.
// Layout: [term(2)][ct(8)][ks(2)][lane(64)][e(8)] bf16.
__global__ void prep_kernel(const float* __restrict__ W1, const float* __restrict__ b1,
                            short* __restrict__ Bpack) {
  int b = blockIdx.x;          // 32 blocks
  int term = b >> 4;
  int ct   = (b >> 1) & 7;
  int ks   = b & 1;
  int l = threadIdx.x;         // 0..63
  int col = ct * 16 + (l & 15);
  int kb  = ks * 32 + (l >> 4) * 8;
  short8 o;
#pragma unroll
  for (int e = 0; e < 8; ++e) {
    int k = kb + e;
    float v = 0.0f;
    if (k < DIN)       v = W1[k * HID + col];
    else if (k == DIN) v = b1[col];
    short hb = bf16_hi(v);
    o[e] = (term == 0) ? hb : bf16_hi(v - bf16_to_f(hb));
  }
  *(short8*)(Bpack + (size_t)(((term * 8 + ct) * 2 + ks) * 64 + l) * 8) = o;
}

// R5/R6 structure + Bpack staged in LDS (kills the 128 KB/block L1 thrash)
// + ~8-tile chunk loop to amortize staging. No cross-tile reg prefetch
// (R7 spill lesson), no launch_bounds min (R2 spill lesson).
__global__ __launch_bounds__(256)
void fused_kernel(const int* __restrict__ t1, const int* __restrict__ t2,
                  const float* __restrict__ numf,
                  const float* __restrict__ tab1, const float* __restrict__ tab2,
                  const short* __restrict__ Bpack,
                  const float* __restrict__ W2, const float* __restrict__ b2,
                  float* __restrict__ out, int N, int ntiles) {
  __shared__ float E1[134][11];     // halo rows base-1..base+128 (+pad rows)
  __shared__ float E2[136][11];     // halo rows base-3..base+130 (+pad rows)
  __shared__ float Cs[BM][22];      // embedding cols d0-19; numeric bypasses LDS
  __shared__ short Bs[16384];       // 32 KB staged W1 hi/lo fragments

  const int tid = threadIdx.x;
  const int wid = tid >> 6, l = tid & 63;
  const int arow = l & 15, kg = l >> 4;
  const int h2 = tid - 122;          // E2 halo row (>=0 for tid>=122)

  // ---- one-time: stage Bpack into LDS (coalesced, conflict-free) ----
  {
    const float4* src = (const float4*)Bpack;   // 2048 x 16B
    float4* dst = (float4*)Bs;
#pragma unroll
    for (int i = 0; i < 8; ++i) dst[tid + 256 * i] = src[tid + 256 * i];
  }
  // W2 column weights + b2 held in regs for the whole kernel
  float w2r[8];
#pragma unroll
  for (int ct = 0; ct < 8; ++ct) w2r[ct] = W2[ct * 16 + (l & 15)];
  const float b2v = b2[0];

  // contiguous tile chunk for this block
  const int q = ntiles / GRID, r = ntiles % GRID;
  int tbeg, tend;
  if ((int)blockIdx.x < r) { tbeg = blockIdx.x * (q + 1); tend = tbeg + q + 1; }
  else { tbeg = r * (q + 1) + ((int)blockIdx.x - r) * q; tend = tbeg + q; }

  for (int t = tbeg; t < tend; ++t) {
    const long base = (long)t * BM;

    // ---- numeric loads for this thread's fragment slots ----
    const long rg0 = base + (long)(wid * 2) * 16 + arow;
    const long rg1 = rg0 + 16;
    float4 qa0 = {0,0,0,0}, qa1 = {0,0,0,0}, qb0 = {0,0,0,0}, qb1 = {0,0,0,0};
    if (kg == 0) {                    // ks1 frag: n12-15
      if (rg0 < (long)N) qa0 = *(const float4*)(numf + rg0 * 16 + 12);
      if (rg1 < (long)N) qa1 = *(const float4*)(numf + rg1 * 16 + 12);
    } else if (kg == 2) {             // k20-23: n0-3
      if (rg0 < (long)N) qa0 = *(const float4*)(numf + rg0 * 16);
      if (rg1 < (long)N) qa1 = *(const float4*)(numf + rg1 * 16);
    } else if (kg == 3) {             // k24-31: n4-11
      if (rg0 < (long)N) { qa0 = *(const float4*)(numf + rg0 * 16 + 4);
                           qb0 = *(const float4*)(numf + rg0 * 16 + 8); }
      if (rg1 < (long)N) { qa1 = *(const float4*)(numf + rg1 * 16 + 4);
                           qb1 = *(const float4*)(numf + rg1 * 16 + 8); }
    }

    // ---- halo gathers (zero-fill outside array) ----
    if (tid < 130) {
      long g = base - 1 + tid;
      if (g >= 0 && g < (long)N) {
        const float2* src = (const float2*)(tab1 + (long)t1[g] * EMB);
#pragma unroll
        for (int i = 0; i < 5; ++i) {
          float2 v = src[i];
          E1[tid][2 * i] = v.x; E1[tid][2 * i + 1] = v.y;
        }
      } else {
#pragma unroll
        for (int i = 0; i < EMB; ++i) E1[tid][i] = 0.0f;
      }
    }
    if (h2 >= 0) {
      long g = base - 3 + h2;
      if (g >= 0 && g < (long)N) {
        const float2* src = (const float2*)(tab2 + (long)t2[g] * EMB);
#pragma unroll
        for (int i = 0; i < 5; ++i) {
          float2 v = src[i];
          E2[h2][2 * i] = v.x; E2[h2][2 * i + 1] = v.y;
        }
      } else {
#pragma unroll
        for (int i = 0; i < EMB; ++i) E2[h2][i] = 0.0f;
      }
    }
    __syncthreads();   // A: E1/E2 ready (covers Bs staging on first iter;
                       //    also fences prev tile's Cs reads vs this build)

    // ---- build: sliding-window tasks -> Cs[0..19] ----
    const bool edgeblk = (base == 0) || (base + BM + 3 > (long)N);
    if (tid < 120) {
      int grp = tid / 10, d = tid - grp * 10;
      int r0 = grp * 11;
      float e[13];
#pragma unroll
      for (int i = 0; i < 13; ++i) e[i] = E1[r0 + i][d];
      if (!edgeblk) {
#pragma unroll
        for (int i = 0; i < 11; ++i) {
          int rr = r0 + i;
          if (rr < BM) Cs[rr][d] = (e[i] + e[i + 1] + e[i + 2]) * (1.0f / 3.0f);
        }
      } else {
#pragma unroll
        for (int i = 0; i < 11; ++i) {
          int rr = r0 + i;
          if (rr < BM) {
            long row = base + rr;
            long lo = row - 1; if (lo < 0) lo = 0;
            long hi = row + 2; if (hi > (long)N) hi = (long)N;
            long c = hi - lo;  if (c < 1) c = 1;
            Cs[rr][d] = (e[i] + e[i + 1] + e[i + 2]) / (float)c;
          }
        }
      }
    } else if (tid < 250) {
      int u = tid - 120;
      int grp = u / 10, d = u - grp * 10;
      int r0 = grp * 10;
      float e[16];
#pragma unroll
      for (int i = 0; i < 16; ++i) e[i] = E2[r0 + i][d];
      float w = e[0] + e[1] + e[2] + e[3] + e[4] + e[5] + e[6];
      if (!edgeblk) {
#pragma unroll
        for (int i = 0; i < 10; ++i) {
          int rr = r0 + i;
          if (rr < BM) Cs[rr][10 + d] = w * (1.0f / 7.0f);
          if (i < 9) w += e[i + 7] - e[i];
        }
      } else {
#pragma unroll
        for (int i = 0; i < 10; ++i) {
          int rr = r0 + i;
          if (rr < BM) {
            long row = base + rr;
            long lo = row - 3; if (lo < 0) lo = 0;
            long hi = row + 4; if (hi > (long)N) hi = (long)N;
            long c = hi - lo;  if (c < 1) c = 1;
            Cs[rr][10 + d] = w / (float)c;
          }
          if (i < 9) w += e[i + 7] - e[i];
        }
      }
    }
    __syncthreads();   // B: Cs ready

    // ---- fragment build (A frag 16x16x32: row=lane&15, k=ks*32+kg*8+e) ----
    short8 aHi[2][2], aLo[2][2];
#pragma unroll
    for (int rtl = 0; rtl < 2; ++rtl) {
      const int rr = (wid * 2 + rtl) * 16 + arow;
      const float* crow = &Cs[rr][0];
      const float4 qa = rtl ? qa1 : qa0;
      const float4 qb = rtl ? qb1 : qb0;
      U8 h0, l0, h1, l1;
      if (kg <= 1) {                 // k0-15: embeddings from Cs
#pragma unroll
        for (int i = 0; i < 4; ++i) {
          float2 tt = *(const float2*)(crow + kg * 8 + 2 * i);
          split_pair(tt.x, tt.y, h0.u[i], l0.u[i]);
        }
      } else if (kg == 2) {          // k16-19 Cs, k20-23 numeric
        float2 t0 = *(const float2*)(crow + 16);
        float2 t1v = *(const float2*)(crow + 18);
        split_pair(t0.x, t0.y, h0.u[0], l0.u[0]);
        split_pair(t1v.x, t1v.y, h0.u[1], l0.u[1]);
        split_pair(qa.x, qa.y, h0.u[2], l0.u[2]);
        split_pair(qa.z, qa.w, h0.u[3], l0.u[3]);
      } else {                       // kg==3: k24-31 numeric n4-11
        split_pair(qa.x, qa.y, h0.u[0], l0.u[0]);
        split_pair(qa.z, qa.w, h0.u[1], l0.u[1]);
        split_pair(qb.x, qb.y, h0.u[2], l0.u[2]);
        split_pair(qb.z, qb.w, h0.u[3], l0.u[3]);
      }
      if (kg == 0) {                 // ks1: k32-35 = n12-15, k36 = bias 1.0
        split_pair(qa.x, qa.y, h1.u[0], l1.u[0]);
        split_pair(qa.z, qa.w, h1.u[1], l1.u[1]);
        h1.u[2] = 0x00003F80u; l1.u[2] = 0u;
        h1.u[3] = 0u;          l1.u[3] = 0u;
      } else {
        h1.u[0] = h1.u[1] = h1.u[2] = h1.u[3] = 0u;
        l1.u[0] = l1.u[1] = l1.u[2] = l1.u[3] = 0u;
      }
      aHi[rtl][0] = h0.v; aLo[rtl][0] = l0.v;
      aHi[rtl][1] = h1.v; aLo[rtl][1] = l1.v;
    }

    // ---- MFMA loop: B-fragments from LDS (conflict-free l*16) ----
    float part[2][4] = {{0,0,0,0},{0,0,0,0}};
#pragma unroll
    for (int ct = 0; ct < 8; ++ct) {
      short8 bh0 = *(const short8*)&Bs[(size_t)(((0*8 + ct)*2 + 0)*64 + l) * 8];
      short8 bh1 = *(const short8*)&Bs[(size_t)(((0*8 + ct)*2 + 1)*64 + l) * 8];
      short8 bl0 = *(const short8*)&Bs[(size_t)(((1*8 + ct)*2 + 0)*64 + l) * 8];
      short8 bl1 = *(const short8*)&Bs[(size_t)(((1*8 + ct)*2 + 1)*64 + l) * 8];
      float w2c = w2r[ct];
#pragma unroll
      for (int rtl = 0; rtl < 2; ++rtl) {
        f32x4 acc = {0.0f, 0.0f, 0.0f, 0.0f};
        acc = __builtin_amdgcn_mfma_f32_16x16x32_bf16(aHi[rtl][0], bh0, acc, 0, 0, 0);
        acc = __builtin_amdgcn_mfma_f32_16x16x32_bf16(aLo[rtl][0], bh0, acc, 0, 0, 0);
        acc = __builtin_amdgcn_mfma_f32_16x16x32_bf16(aHi[rtl][0], bl0, acc, 0, 0, 0);
        acc = __builtin_amdgcn_mfma_f32_16x16x32_bf16(aHi[rtl][1], bh1, acc, 0, 0, 0);
        acc = __builtin_amdgcn_mfma_f32_16x16x32_bf16(aLo[rtl][1], bh1, acc, 0, 0, 0);
        acc = __builtin_amdgcn_mfma_f32_16x16x32_bf16(aHi[rtl][1], bl1, acc, 0, 0, 0);
#pragma unroll
        for (int rg = 0; rg < 4; ++rg) {
          float hv = fmaxf(acc[rg], 0.0f);   // relu(h + b1), b1 via k36 bias row
          part[rtl][rg] += hv * w2c;
        }
      }
    }
    // reduce W2 dot across the 16 column-lanes
#pragma unroll
    for (int off = 1; off < 16; off <<= 1) {
#pragma unroll
      for (int rtl = 0; rtl < 2; ++rtl)
#pragma unroll
        for (int rg = 0; rg < 4; ++rg)
          part[rtl][rg] += __shfl_xor(part[rtl][rg], off, 64);
    }
    if ((l & 15) < 4) {
#pragma unroll
      for (int rtl = 0; rtl < 2; ++rtl) {
        int rt = wid * 2 + rtl;
        long grow = base + rt * 16 + (l >> 4) * 4 + (l & 15);
        if (grow < (long)N) {
          float x = part[rtl][l & 15] + b2v;
          out[grow] = 1.0f / (1.0f + exp2f(x * -1.44269504f));
        }
      }
    }
    // loop back: next tile's E-writes come after this wave's barrier B, so
    // all build-phase E reads of tile t are complete (2 barriers/tile total).
  }
}

extern "C" void kernel_launch(void* const* d_in, const int* in_sizes, int n_in,
                              void* d_out, int out_size, void* d_ws, size_t ws_size,
                              hipStream_t stream) {
  const int*   t1   = (const int*)d_in[0];
  const int*   t2   = (const int*)d_in[1];
  const float* numf = (const float*)d_in[2];
  const float* tab1 = (const float*)d_in[3];
  const float* tab2 = (const float*)d_in[4];
  const float* W1   = (const float*)d_in[5];
  const float* b1   = (const float*)d_in[6];
  const float* W2   = (const float*)d_in[7];
  const float* b2   = (const float*)d_in[8];
  float* out = (float*)d_out;
  const int N = in_sizes[0];
  short* Bpack = (short*)d_ws;   // 32 KB

  hipLaunchKernelGGL(prep_kernel, dim3(32), dim3(64), 0, stream, W1, b1, Bpack);
  int ntiles = (N + BM - 1) / BM;
  hipLaunchKernelGGL(fused_kernel, dim3(GRID), dim3(256), 0, stream,
                     t1, t2, numf, tab1, tab2, Bpack, W2, b2, out, N, ntiles);
}